// Round 3
// baseline (339.365 us; speedup 1.0000x reference)
//
#include <hip/hip_runtime.h>

typedef __attribute__((ext_vector_type(4))) float f32x4;
typedef __attribute__((ext_vector_type(4))) unsigned short u16x4;
typedef __attribute__((ext_vector_type(8))) unsigned short u16x8;
typedef __attribute__((ext_vector_type(8))) __bf16 bf16x8;

__device__ __forceinline__ unsigned short f2bf(float f) {
  unsigned int u = __builtin_bit_cast(unsigned int, f);
  u += 0x7fffu + ((u >> 16) & 1u);
  return (unsigned short)(u >> 16);
}

__device__ __forceinline__ bf16x8 ld_bf8(const unsigned short* p) {
  return __builtin_bit_cast(bf16x8, *(const u16x8*)p);
}

__device__ __forceinline__ f32x4 mfma16(bf16x8 a, bf16x8 b, f32x4 c) {
  return __builtin_amdgcn_mfma_f32_16x16x32_bf16(a, b, c, 0, 0, 0);
}

// ---------------- fp32 -> bf16 convert ----------------
__global__ void cvt_kernel(const float* __restrict__ in,
                           unsigned short* __restrict__ out, int n) {
  int i = (blockIdx.x * 256 + threadIdx.x) * 4;
  if (i >= n) return;
  f32x4 v = *(const f32x4*)(in + i);
  u16x4 r;
  r[0] = f2bf(v[0]); r[1] = f2bf(v[1]); r[2] = f2bf(v[2]); r[3] = f2bf(v[3]);
  *(u16x4*)(out + i) = r;
}

// ---------------- GEMM: C[m,n] = sum_k A[m,k]*W[n,k] + bias[n] ----------------
// A: [M,512] bf16 row-major, W: [N,512] bf16 row-major (i.e. B^T layout).
// EPI 0: bf16 out [M,512]; EPI 1: bf16 out transposed per-head Vt[b,h,d,s];
// EPI 2: fp32 out [M,512].
template <int EPI>
__global__ __launch_bounds__(256) void gemm_bt(const unsigned short* __restrict__ A,
                                               const unsigned short* __restrict__ Bw,
                                               const float* __restrict__ bias,
                                               void* __restrict__ Cout) {
  const int l = threadIdx.x & 63;
  const int w = threadIdx.x >> 6;
  const int g = l >> 4;
  const int lr = l & 15;
  const int m0 = blockIdx.y * 128 + (w >> 1) * 64;
  const int n0 = blockIdx.x * 128 + (w & 1) * 64;

  f32x4 acc[4][4];
#pragma unroll
  for (int i = 0; i < 4; i++)
#pragma unroll
    for (int j = 0; j < 4; j++) acc[i][j] = f32x4{0.f, 0.f, 0.f, 0.f};

  const unsigned short* pA = A + (size_t)(m0 + lr) * 512 + g * 8;
  const unsigned short* pB = Bw + (size_t)(n0 + lr) * 512 + g * 8;

  for (int k = 0; k < 512; k += 32) {
    bf16x8 af[4], bfr[4];
#pragma unroll
    for (int t = 0; t < 4; t++) af[t] = ld_bf8(pA + t * (16 * 512) + k);
#pragma unroll
    for (int t = 0; t < 4; t++) bfr[t] = ld_bf8(pB + t * (16 * 512) + k);
#pragma unroll
    for (int i = 0; i < 4; i++)
#pragma unroll
      for (int j = 0; j < 4; j++)
        acc[i][j] = mfma16(af[i], bfr[j], acc[i][j]);
  }

#pragma unroll
  for (int j = 0; j < 4; j++) {
    const int n = n0 + j * 16 + lr;
    const float bn = bias[n];
#pragma unroll
    for (int i = 0; i < 4; i++) {
#pragma unroll
      for (int r = 0; r < 4; r++) {
        const int m = m0 + i * 16 + g * 4 + r;
        const float v = acc[i][j][r] + bn;
        if (EPI == 0) {
          ((unsigned short*)Cout)[(size_t)m * 512 + n] = f2bf(v);
        } else if (EPI == 1) {
          const int bb = m >> 11, s = m & 2047;
          const int hh = n >> 6, d = n & 63;
          ((unsigned short*)Cout)[((size_t)((bb * 8 + hh) * 64 + d) << 11) + s] = f2bf(v);
        } else {
          ((float*)Cout)[(size_t)m * 512 + n] = v;
        }
      }
    }
  }
}

// ---------------- flash attention with relative-position bias ----------------
// Qp/Kp: [B*2048, 512] bf16 (head slice at h*64). Vt: [B,H,64,2048] bf16.
// Out: [B*2048, 512] bf16 (concat heads). One block = (b,h, 64 q-rows); wave = 16 q-rows.
__global__ __launch_bounds__(256) void attn_kernel(const unsigned short* __restrict__ Qp,
                                                   const unsigned short* __restrict__ Kp,
                                                   const unsigned short* __restrict__ Vt,
                                                   const float* __restrict__ rel_emb,
                                                   unsigned short* __restrict__ Out) {
  __shared__ float bias_s[257];
  const int bid = blockIdx.x;
  const int qb = bid & 31;
  const int h = (bid >> 5) & 7;
  const int b = bid >> 8;
  const int tid = threadIdx.x;
  for (int i = tid; i < 257; i += 256) bias_s[i] = rel_emb[i * 8 + h] * 1.44269504f;
  __syncthreads();

  const int l = tid & 63, w = tid >> 6;
  const int g = l >> 4, q = l & 15;
  const int q0 = qb * 64 + w * 16;
  const int tq = q0 + q;  // this lane's q-row (softmax state lives here)

  const unsigned short* qptr = Qp + (size_t)(b * 2048 + tq) * 512 + h * 64 + g * 8;
  const bf16x8 qlo = ld_bf8(qptr);
  const bf16x8 qhi = ld_bf8(qptr + 32);
  const unsigned short* kbase = Kp + (size_t)(b * 2048) * 512 + h * 64 + g * 8;
  const unsigned short* vbase = Vt + (((size_t)((b * 8 + h) * 64)) << 11) + g * 8;

  float m_run = -1e30f, l_run = 0.f;
  f32x4 o[4];
#pragma unroll
  for (int dt = 0; dt < 4; dt++) o[dt] = f32x4{0.f, 0.f, 0.f, 0.f};
  const f32x4 zero = {0.f, 0.f, 0.f, 0.f};
  const float SCL = 0.125f * 1.44269504f;  // 1/sqrt(64) * log2(e)

  for (int s0 = 0; s0 < 2048; s0 += 32) {
    // K fragments: A-operand rows = kv (lane&15), k = head-dim (g*8+j)
    const unsigned short* kr = kbase + (size_t)(s0 + q) * 512;
    const bf16x8 k0l = ld_bf8(kr);
    const bf16x8 k0h = ld_bf8(kr + 32);
    const bf16x8 k1l = ld_bf8(kr + 16 * 512);
    const bf16x8 k1h = ld_bf8(kr + 16 * 512 + 32);

    // swapped QK^T: D[kv, q]; lane holds col=q (l&15), rows kv=g*4+r
    f32x4 sc0 = mfma16(k0l, qlo, zero); sc0 = mfma16(k0h, qhi, sc0);
    f32x4 sc1 = mfma16(k1l, qlo, zero); sc1 = mfma16(k1h, qhi, sc1);

    float x0[4], x1[4];
    float mx = -1e30f;
#pragma unroll
    for (int r = 0; r < 4; r++) {
      const int sA = s0 + g * 4 + r;
      const int sB = sA + 16;
      int iA = tq - sA; iA = (iA < -128 ? -128 : (iA > 128 ? 128 : iA)) + 128;
      int iB = tq - sB; iB = (iB < -128 ? -128 : (iB > 128 ? 128 : iB)) + 128;
      x0[r] = sc0[r] * SCL + bias_s[iA];
      x1[r] = sc1[r] * SCL + bias_s[iB];
      mx = fmaxf(mx, fmaxf(x0[r], x1[r]));
    }
    // reduce over kv: 4-lane group (same l&15) holds the full 32-kv row
    mx = fmaxf(mx, __shfl_xor(mx, 16, 64));
    mx = fmaxf(mx, __shfl_xor(mx, 32, 64));
    const float m_new = fmaxf(m_run, mx);
    const float rescale = exp2f(m_run - m_new);
    float psum = 0.f;
#pragma unroll
    for (int r = 0; r < 4; r++) {
      x0[r] = exp2f(x0[r] - m_new);
      x1[r] = exp2f(x1[r] - m_new);
      psum += x0[r] + x1[r];
    }
    psum += __shfl_xor(psum, 16, 64);
    psum += __shfl_xor(psum, 32, 64);
    l_run = l_run * rescale + psum;
    m_run = m_new;

    // distribute per-q rescale to O layout (lane holds rows q=g*4+r)
    float rs[4];
#pragma unroll
    for (int r = 0; r < 4; r++) rs[r] = __shfl(rescale, g * 4 + r, 64);
#pragma unroll
    for (int dt = 0; dt < 4; dt++) {
#pragma unroll
      for (int r = 0; r < 4; r++) o[dt][r] *= rs[r];
    }

    // redistribute P into PV A-fragment layout: lane needs P[q=l&15][kv=g*8+j]
    u16x8 pu;
#pragma unroll
    for (int j = 0; j < 8; j++) {
      const int kv = g * 8 + j;
      const int src = q | (((kv >> 2) & 3) << 4);
      const float v0 = __shfl(x0[j & 3], src, 64);
      const float v1 = __shfl(x1[j & 3], src, 64);
      pu[j] = f2bf(g >= 2 ? v1 : v0);
    }
    const bf16x8 pfrag = __builtin_bit_cast(bf16x8, pu);

    // PV: D[q, d] += P[q, kv32] * V[kv32, d]; V B-operand from transposed Vt rows
#pragma unroll
    for (int dt = 0; dt < 4; dt++) {
      const bf16x8 vf = ld_bf8(vbase + ((size_t)(dt * 16 + q) << 11) + s0);
      o[dt] = mfma16(pfrag, vf, o[dt]);
    }
  }

  float inv[4];
#pragma unroll
  for (int r = 0; r < 4; r++) inv[r] = 1.f / __shfl(l_run, g * 4 + r, 64);
  unsigned short* obase = Out + (size_t)(b * 2048 + q0) * 512 + h * 64;
#pragma unroll
  for (int dt = 0; dt < 4; dt++) {
#pragma unroll
    for (int r = 0; r < 4; r++) {
      obase[(size_t)(g * 4 + r) * 512 + dt * 16 + q] = f2bf(o[dt][r] * inv[r]);
    }
  }
}

// ---------------- host ----------------
extern "C" void kernel_launch(void* const* d_in, const int* in_sizes, int n_in,
                              void* d_out, int out_size, void* d_ws, size_t ws_size,
                              hipStream_t stream) {
  const float* query = (const float*)d_in[0];
  const float* key   = (const float*)d_in[1];
  const float* value = (const float*)d_in[2];
  const float* Wq = (const float*)d_in[3];
  const float* bq = (const float*)d_in[4];
  const float* Wk = (const float*)d_in[5];
  const float* bk = (const float*)d_in[6];
  const float* Wv = (const float*)d_in[7];
  const float* bv = (const float*)d_in[8];
  const float* Wo = (const float*)d_in[9];
  const float* bo = (const float*)d_in[10];
  const float* rel = (const float*)d_in[11];

  char* ws = (char*)d_ws;
  const size_t SZX = (size_t)4 * 2048 * 512;  // elements per activation tensor
  const size_t SZW = (size_t)512 * 512;
  unsigned short* xq = (unsigned short*)ws;
  unsigned short* xk = xq + SZX;
  unsigned short* xv = xk + SZX;
  unsigned short* wq = xv + SZX;
  unsigned short* wk = wq + SZW;
  unsigned short* wv = wk + SZW;
  unsigned short* wo = wv + SZW;
  unsigned short* Qp = wo + SZW;
  unsigned short* Kp = Qp + SZX;
  unsigned short* Vt = Kp + SZX;
  unsigned short* At = Vt + SZX;

  auto cvt = [&](const float* s, unsigned short* dst, int n) {
    cvt_kernel<<<dim3((n + 1023) / 1024), dim3(256), 0, stream>>>(s, dst, n);
  };
  cvt(query, xq, (int)SZX);
  cvt(key, xk, (int)SZX);
  cvt(value, xv, (int)SZX);
  cvt(Wq, wq, (int)SZW);
  cvt(Wk, wk, (int)SZW);
  cvt(Wv, wv, (int)SZW);
  cvt(Wo, wo, (int)SZW);

  dim3 gg(4, 64), blk(256);
  gemm_bt<0><<<gg, blk, 0, stream>>>(xq, wq, bq, (void*)Qp);
  gemm_bt<0><<<gg, blk, 0, stream>>>(xk, wk, bk, (void*)Kp);
  gemm_bt<1><<<gg, blk, 0, stream>>>(xv, wv, bv, (void*)Vt);

  attn_kernel<<<dim3(1024), blk, 0, stream>>>(Qp, Kp, Vt, rel, At);

  gemm_bt<2><<<gg, blk, 0, stream>>>(At, wo, bo, d_out);
}

// Round 4
// 230.897 us; speedup vs baseline: 1.4698x; 1.4698x over previous
//
#include <hip/hip_runtime.h>

typedef __attribute__((ext_vector_type(4))) float f32x4;
typedef __attribute__((ext_vector_type(16))) float f32x16;
typedef __attribute__((ext_vector_type(4))) unsigned short u16x4;
typedef __attribute__((ext_vector_type(8))) unsigned short u16x8;
typedef __attribute__((ext_vector_type(4))) unsigned int u32x4;
typedef __attribute__((ext_vector_type(8))) __bf16 bf16x8;

__device__ __forceinline__ unsigned short f2bf(float f) {
  unsigned int u = __builtin_bit_cast(unsigned int, f);
  u += 0x7fffu + ((u >> 16) & 1u);
  return (unsigned short)(u >> 16);
}

__device__ __forceinline__ bf16x8 ld_bf8(const unsigned short* p) {
  return __builtin_bit_cast(bf16x8, *(const u16x8*)p);
}

__device__ __forceinline__ f32x4 mfma16(bf16x8 a, bf16x8 b, f32x4 c) {
  return __builtin_amdgcn_mfma_f32_16x16x32_bf16(a, b, c, 0, 0, 0);
}

__device__ __forceinline__ f32x16 mfma32(bf16x8 a, bf16x8 b, f32x16 c) {
  return __builtin_amdgcn_mfma_f32_32x32x16_bf16(a, b, c, 0, 0, 0);
}

__device__ __forceinline__ unsigned int cvt_pk_bf16(float lo, float hi) {
  unsigned int r;
  asm("v_cvt_pk_bf16_f32 %0, %1, %2" : "=v"(r) : "v"(lo), "v"(hi));
  return r;
}

// swaps a's upper-32-lane values with b's lower-32-lane values:
// after: a = [a.lo32 | b.lo32], b = [a.hi32 | b.hi32]
__device__ __forceinline__ void plane32_swap(unsigned int& a, unsigned int& b) {
  asm("v_permlane32_swap_b32 %0, %1" : "+v"(a), "+v"(b));
}

// ---------------- fp32 -> bf16 convert ----------------
__global__ void cvt_kernel(const float* __restrict__ in,
                           unsigned short* __restrict__ out, int n) {
  int i = (blockIdx.x * 256 + threadIdx.x) * 4;
  if (i >= n) return;
  f32x4 v = *(const f32x4*)(in + i);
  u16x4 r;
  r[0] = f2bf(v[0]); r[1] = f2bf(v[1]); r[2] = f2bf(v[2]); r[3] = f2bf(v[3]);
  *(u16x4*)(out + i) = r;
}

// ---------------- GEMM: C[m,n] = sum_k A[m,k]*W[n,k] + bias[n] ----------------
template <int EPI>
__global__ __launch_bounds__(256) void gemm_bt(const unsigned short* __restrict__ A,
                                               const unsigned short* __restrict__ Bw,
                                               const float* __restrict__ bias,
                                               void* __restrict__ Cout) {
  const int l = threadIdx.x & 63;
  const int w = threadIdx.x >> 6;
  const int g = l >> 4;
  const int lr = l & 15;
  const int m0 = blockIdx.y * 128 + (w >> 1) * 64;
  const int n0 = blockIdx.x * 128 + (w & 1) * 64;

  f32x4 acc[4][4];
#pragma unroll
  for (int i = 0; i < 4; i++)
#pragma unroll
    for (int j = 0; j < 4; j++) acc[i][j] = f32x4{0.f, 0.f, 0.f, 0.f};

  const unsigned short* pA = A + (size_t)(m0 + lr) * 512 + g * 8;
  const unsigned short* pB = Bw + (size_t)(n0 + lr) * 512 + g * 8;

  for (int k = 0; k < 512; k += 32) {
    bf16x8 af[4], bfr[4];
#pragma unroll
    for (int t = 0; t < 4; t++) af[t] = ld_bf8(pA + t * (16 * 512) + k);
#pragma unroll
    for (int t = 0; t < 4; t++) bfr[t] = ld_bf8(pB + t * (16 * 512) + k);
#pragma unroll
    for (int i = 0; i < 4; i++)
#pragma unroll
      for (int j = 0; j < 4; j++)
        acc[i][j] = mfma16(af[i], bfr[j], acc[i][j]);
  }

#pragma unroll
  for (int j = 0; j < 4; j++) {
    const int n = n0 + j * 16 + lr;
    const float bn = bias[n];
#pragma unroll
    for (int i = 0; i < 4; i++) {
#pragma unroll
      for (int r = 0; r < 4; r++) {
        const int m = m0 + i * 16 + g * 4 + r;
        const float v = acc[i][j][r] + bn;
        if (EPI == 0) {
          ((unsigned short*)Cout)[(size_t)m * 512 + n] = f2bf(v);
        } else if (EPI == 1) {
          const int bb = m >> 11, s = m & 2047;
          const int hh = n >> 6, d = n & 63;
          ((unsigned short*)Cout)[((size_t)((bb * 8 + hh) * 64 + d) << 11) + s] = f2bf(v);
        } else {
          ((float*)Cout)[(size_t)m * 512 + n] = v;
        }
      }
    }
  }
}

// ---------------- flash attention, 32x32 MFMA + in-register softmax ----------------
// Qp/Kp: [B*2048, 512] bf16 (head slice at h*64). Vt: [B,H,64,2048] bf16.
// Out: [B*2048, 512] bf16. Block = 4 waves; wave = 32 q-rows; KV tile = 64.
// Swapped QK^T: lane (hi=l>>5, q=l&31) holds P[kv rows R(hi)][q]; softmax state per q.
__global__ __launch_bounds__(256, 2) void attn_kernel(const unsigned short* __restrict__ Qp,
                                                      const unsigned short* __restrict__ Kp,
                                                      const unsigned short* __restrict__ Vt,
                                                      const float* __restrict__ rel_emb,
                                                      unsigned short* __restrict__ Out) {
  __shared__ float bias_s[257];
  const int bid = blockIdx.x;
  const int qb = bid & 15;
  const int h = (bid >> 4) & 7;
  const int b = bid >> 7;
  const int tid = threadIdx.x;
  for (int i = tid; i < 257; i += 256) bias_s[i] = rel_emb[i * 8 + h] * 1.44269504f;
  __syncthreads();
  const float bias_lo = bias_s[0], bias_hi = bias_s[256];

  const int lane = tid & 63, w = tid >> 6;
  const int hi = lane >> 5, q31 = lane & 31;
  const int q0w = qb * 128 + w * 32;
  const int tq = q0w + q31;
  const float SCL = 0.125f * 1.44269504f;  // 1/sqrt(64) * log2(e)

  // Q fragments (B-operand of 32x32x16: col=q31, k=hi*8+j), d-chunks of 16
  const unsigned short* qptr = Qp + (size_t)(b * 2048 + tq) * 512 + h * 64 + hi * 8;
  bf16x8 qf[4];
#pragma unroll
  for (int dc = 0; dc < 4; dc++) qf[dc] = ld_bf8(qptr + dc * 16);

  const unsigned short* kbase = Kp + (size_t)(b * 2048) * 512 + h * 64 + hi * 8;
  const unsigned short* vb_lo = Vt + (((size_t)((b * 8 + h) * 64 + q31)) << 11) + hi * 8;
  const unsigned short* vb_hi = vb_lo + ((size_t)32 << 11);

  const f32x16 z16 = {0.f, 0.f, 0.f, 0.f, 0.f, 0.f, 0.f, 0.f,
                      0.f, 0.f, 0.f, 0.f, 0.f, 0.f, 0.f, 0.f};
  f32x16 o_lo = z16, o_hi = z16;
  float m_run = -1e30f, l_run = 0.f;

  for (int s0 = 0; s0 < 2048; s0 += 64) {
    // ---- QK^T (swapped): two independent 32-kv chains ----
    const unsigned short* krA = kbase + (size_t)(s0 + q31) * 512;
    const unsigned short* krB = krA + 32 * 512;
    f32x16 sa = mfma32(ld_bf8(krA), qf[0], z16);
    f32x16 sb = mfma32(ld_bf8(krB), qf[0], z16);
    sa = mfma32(ld_bf8(krA + 16), qf[1], sa);
    sb = mfma32(ld_bf8(krB + 16), qf[1], sb);
    sa = mfma32(ld_bf8(krA + 32), qf[2], sa);
    sb = mfma32(ld_bf8(krB + 32), qf[2], sb);
    sa = mfma32(ld_bf8(krA + 48), qf[3], sa);
    sb = mfma32(ld_bf8(krB + 48), qf[3], sb);

    // ---- V fragments (issue early; latency hides under softmax VALU) ----
    bf16x8 vl[4], vh[4];
#pragma unroll
    for (int ks = 0; ks < 4; ks++) {
      vl[ks] = ld_bf8(vb_lo + s0 + ks * 16);
      vh[ks] = ld_bf8(vb_hi + s0 + ks * 16);
    }

    // ---- bias + scale (wave-uniform clamped fast path) ----
    float x[32];
    const int relmin = q0w - s0 - 63;
    const int relmax = q0w + 31 - s0;
    if (relmin >= 128 || relmax <= -128) {
      const float bc = (relmin >= 128) ? bias_hi : bias_lo;
#pragma unroll
      for (int r = 0; r < 16; r++) {
        x[r] = fmaf(sa[r], SCL, bc);
        x[16 + r] = fmaf(sb[r], SCL, bc);
      }
    } else {
#pragma unroll
      for (int r = 0; r < 16; r++) {
        const int rowA = (r & 3) + 8 * (r >> 2) + 4 * hi;
        const int rA = tq - s0 - rowA;
        const int rB = rA - 32;
        const int iA = (rA < -128 ? -128 : (rA > 128 ? 128 : rA)) + 128;
        const int iB = (rB < -128 ? -128 : (rB > 128 ? 128 : rB)) + 128;
        x[r] = fmaf(sa[r], SCL, bias_s[iA]);
        x[16 + r] = fmaf(sb[r], SCL, bias_s[iB]);
      }
    }

    // ---- row max (tree) + cross-half combine ----
    float m8[8];
#pragma unroll
    for (int i = 0; i < 8; i++)
      m8[i] = fmaxf(fmaxf(x[i], x[i + 8]), fmaxf(x[i + 16], x[i + 24]));
    float mx = fmaxf(fmaxf(fmaxf(m8[0], m8[1]), fmaxf(m8[2], m8[3])),
                     fmaxf(fmaxf(m8[4], m8[5]), fmaxf(m8[6], m8[7])));
    mx = fmaxf(mx, __shfl_xor(mx, 32, 64));

    // ---- defer-max: rescale only if some row grew past threshold ----
    if (!__all(mx <= m_run + 8.f)) {
      const float m_new = fmaxf(m_run, mx);
      const float rsq = exp2f(m_run - m_new);
      l_run *= rsq;
      m_run = m_new;
#pragma unroll
      for (int r2 = 0; r2 < 16; r2++) {
        const int ro = (r2 & 3) + 8 * (r2 >> 2) + 4 * hi;
        const float rr = __shfl(rsq, ro, 64);
        o_lo[r2] *= rr;
        o_hi[r2] *= rr;
      }
    }

    // ---- exp2 + sum (tree) ----
#pragma unroll
    for (int i = 0; i < 32; i++) x[i] = exp2f(x[i] - m_run);
    float s8[8];
#pragma unroll
    for (int i = 0; i < 8; i++)
      s8[i] = (x[i] + x[i + 8]) + (x[i + 16] + x[i + 24]);
    float ps = ((s8[0] + s8[1]) + (s8[2] + s8[3])) + ((s8[4] + s8[5]) + (s8[6] + s8[7]));
    ps += __shfl_xor(ps, 32, 64);
    l_run += ps;

    // ---- P -> PV A-fragments via cvt_pk + permlane32_swap ----
    bf16x8 pa[4];
#pragma unroll
    for (int ks = 0; ks < 4; ks++) {
      const int c8 = ks * 8;
      unsigned int a0 = cvt_pk_bf16(x[c8 + 0], x[c8 + 1]);
      unsigned int b0 = cvt_pk_bf16(x[c8 + 4], x[c8 + 5]);
      unsigned int a1 = cvt_pk_bf16(x[c8 + 2], x[c8 + 3]);
      unsigned int b1 = cvt_pk_bf16(x[c8 + 6], x[c8 + 7]);
      plane32_swap(a0, b0);  // a0 = word0 (k0,k1), b0 = word2 (k4,k5)
      plane32_swap(a1, b1);  // a1 = word1 (k2,k3), b1 = word3 (k6,k7)
      pa[ks] = __builtin_bit_cast(bf16x8, u32x4{a0, a1, b0, b1});
    }

    // ---- PV: O[q][d] += P * V ----
#pragma unroll
    for (int ks = 0; ks < 4; ks++) {
      o_lo = mfma32(pa[ks], vl[ks], o_lo);
      o_hi = mfma32(pa[ks], vh[ks], o_hi);
    }
  }

  // ---- normalize + write ----
  const float inv = 1.f / l_run;
#pragma unroll
  for (int r2 = 0; r2 < 16; r2++) {
    const int ro = (r2 & 3) + 8 * (r2 >> 2) + 4 * hi;
    const float rr = __shfl(inv, ro, 64);
    unsigned short* op = Out + (size_t)(b * 2048 + q0w + ro) * 512 + h * 64;
    op[q31] = f2bf(o_lo[r2] * rr);
    op[32 + q31] = f2bf(o_hi[r2] * rr);
  }
}

// ---------------- host ----------------
extern "C" void kernel_launch(void* const* d_in, const int* in_sizes, int n_in,
                              void* d_out, int out_size, void* d_ws, size_t ws_size,
                              hipStream_t stream) {
  const float* query = (const float*)d_in[0];
  const float* key   = (const float*)d_in[1];
  const float* value = (const float*)d_in[2];
  const float* Wq = (const float*)d_in[3];
  const float* bq = (const float*)d_in[4];
  const float* Wk = (const float*)d_in[5];
  const float* bk = (const float*)d_in[6];
  const float* Wv = (const float*)d_in[7];
  const float* bv = (const float*)d_in[8];
  const float* Wo = (const float*)d_in[9];
  const float* bo = (const float*)d_in[10];
  const float* rel = (const float*)d_in[11];

  char* ws = (char*)d_ws;
  const size_t SZX = (size_t)4 * 2048 * 512;
  const size_t SZW = (size_t)512 * 512;
  unsigned short* xq = (unsigned short*)ws;
  unsigned short* xk = xq + SZX;
  unsigned short* xv = xk + SZX;
  unsigned short* wq = xv + SZX;
  unsigned short* wk = wq + SZW;
  unsigned short* wv = wk + SZW;
  unsigned short* wo = wv + SZW;
  unsigned short* Qp = wo + SZW;
  unsigned short* Kp = Qp + SZX;
  unsigned short* Vt = Kp + SZX;
  unsigned short* At = Vt + SZX;

  auto cvt = [&](const float* s, unsigned short* dst, int n) {
    cvt_kernel<<<dim3((n + 1023) / 1024), dim3(256), 0, stream>>>(s, dst, n);
  };
  cvt(query, xq, (int)SZX);
  cvt(key, xk, (int)SZX);
  cvt(value, xv, (int)SZX);
  cvt(Wq, wq, (int)SZW);
  cvt(Wk, wk, (int)SZW);
  cvt(Wv, wv, (int)SZW);
  cvt(Wo, wo, (int)SZW);

  dim3 gg(4, 64), blk(256);
  gemm_bt<0><<<gg, blk, 0, stream>>>(xq, wq, bq, (void*)Qp);
  gemm_bt<0><<<gg, blk, 0, stream>>>(xk, wk, bk, (void*)Kp);
  gemm_bt<1><<<gg, blk, 0, stream>>>(xv, wv, bv, (void*)Vt);

  attn_kernel<<<dim3(512), blk, 0, stream>>>(Qp, Kp, Vt, rel, At);

  gemm_bt<2><<<gg, blk, 0, stream>>>(At, wo, bo, d_out);
}

// Round 5
// 228.243 us; speedup vs baseline: 1.4869x; 1.0116x over previous
//
#include <hip/hip_runtime.h>

typedef __attribute__((ext_vector_type(4))) float f32x4;
typedef __attribute__((ext_vector_type(16))) float f32x16;
typedef __attribute__((ext_vector_type(4))) unsigned short u16x4;
typedef __attribute__((ext_vector_type(8))) unsigned short u16x8;
typedef __attribute__((ext_vector_type(4))) unsigned int u32x4;
typedef __attribute__((ext_vector_type(8))) __bf16 bf16x8;

__device__ __forceinline__ unsigned short f2bf(float f) {
  unsigned int u = __builtin_bit_cast(unsigned int, f);
  u += 0x7fffu + ((u >> 16) & 1u);
  return (unsigned short)(u >> 16);
}

__device__ __forceinline__ bf16x8 ld_bf8(const unsigned short* p) {
  return __builtin_bit_cast(bf16x8, *(const u16x8*)p);
}

__device__ __forceinline__ f32x4 mfma16(bf16x8 a, bf16x8 b, f32x4 c) {
  return __builtin_amdgcn_mfma_f32_16x16x32_bf16(a, b, c, 0, 0, 0);
}

__device__ __forceinline__ f32x16 mfma32(bf16x8 a, bf16x8 b, f32x16 c) {
  return __builtin_amdgcn_mfma_f32_32x32x16_bf16(a, b, c, 0, 0, 0);
}

__device__ __forceinline__ unsigned int cvt_pk_bf16(float lo, float hi) {
  unsigned int r;
  asm("v_cvt_pk_bf16_f32 %0, %1, %2" : "=v"(r) : "v"(lo), "v"(hi));
  return r;
}

__device__ __forceinline__ void plane32_swap(unsigned int& a, unsigned int& b) {
  asm("v_permlane32_swap_b32 %0, %1" : "+v"(a), "+v"(b));
}

// ---------------- fp32 -> bf16 convert ----------------
__global__ void cvt_kernel(const float* __restrict__ in,
                           unsigned short* __restrict__ out, int n) {
  int i = (blockIdx.x * 256 + threadIdx.x) * 4;
  if (i >= n) return;
  f32x4 v = *(const f32x4*)(in + i);
  u16x4 r;
  r[0] = f2bf(v[0]); r[1] = f2bf(v[1]); r[2] = f2bf(v[2]); r[3] = f2bf(v[3]);
  *(u16x4*)(out + i) = r;
}

// ---------------- GEMM: C[m,n] = sum_k A[m,k]*W[n,k] + bias[n] ----------------
template <int EPI>
__global__ __launch_bounds__(256) void gemm_bt(const unsigned short* __restrict__ A,
                                               const unsigned short* __restrict__ Bw,
                                               const float* __restrict__ bias,
                                               void* __restrict__ Cout) {
  const int l = threadIdx.x & 63;
  const int w = threadIdx.x >> 6;
  const int g = l >> 4;
  const int lr = l & 15;
  const int m0 = blockIdx.y * 128 + (w >> 1) * 64;
  const int n0 = blockIdx.x * 128 + (w & 1) * 64;

  f32x4 acc[4][4];
#pragma unroll
  for (int i = 0; i < 4; i++)
#pragma unroll
    for (int j = 0; j < 4; j++) acc[i][j] = f32x4{0.f, 0.f, 0.f, 0.f};

  const unsigned short* pA = A + (size_t)(m0 + lr) * 512 + g * 8;
  const unsigned short* pB = Bw + (size_t)(n0 + lr) * 512 + g * 8;

  for (int k = 0; k < 512; k += 32) {
    bf16x8 af[4], bfr[4];
#pragma unroll
    for (int t = 0; t < 4; t++) af[t] = ld_bf8(pA + t * (16 * 512) + k);
#pragma unroll
    for (int t = 0; t < 4; t++) bfr[t] = ld_bf8(pB + t * (16 * 512) + k);
#pragma unroll
    for (int i = 0; i < 4; i++)
#pragma unroll
      for (int j = 0; j < 4; j++)
        acc[i][j] = mfma16(af[i], bfr[j], acc[i][j]);
  }

#pragma unroll
  for (int j = 0; j < 4; j++) {
    const int n = n0 + j * 16 + lr;
    const float bn = bias[n];
#pragma unroll
    for (int i = 0; i < 4; i++) {
#pragma unroll
      for (int r = 0; r < 4; r++) {
        const int m = m0 + i * 16 + g * 4 + r;
        const float v = acc[i][j][r] + bn;
        if (EPI == 0) {
          ((unsigned short*)Cout)[(size_t)m * 512 + n] = f2bf(v);
        } else if (EPI == 1) {
          const int bb = m >> 11, s = m & 2047;
          const int hh = n >> 6, d = n & 63;
          ((unsigned short*)Cout)[((size_t)((bb * 8 + hh) * 64 + d) << 11) + s] = f2bf(v);
        } else {
          ((float*)Cout)[(size_t)m * 512 + n] = v;
        }
      }
    }
  }
}

// ---------------- flash attention, 32x32 MFMA, software-pipelined ----------------
// Qp/Kp: [B*2048, 512] bf16 (head slice at h*64). Vt: [B,H,64,2048] bf16.
// Block = 4 waves; wave = 32 q-rows; KV tile = 64.
// Pipeline: softmax(t) || QK^T(t+1) MFMA; PV(t) executes under softmax(t+1).
__global__ __launch_bounds__(256, 2) void attn_kernel(const unsigned short* __restrict__ Qp,
                                                      const unsigned short* __restrict__ Kp,
                                                      const unsigned short* __restrict__ Vt,
                                                      const float* __restrict__ rel_emb,
                                                      unsigned short* __restrict__ Out) {
  __shared__ float bias_s[257];
  const int bid = blockIdx.x;
  const int qb = bid & 15;
  const int h = (bid >> 4) & 7;
  const int b = bid >> 7;
  const int tid = threadIdx.x;
  for (int i = tid; i < 257; i += 256) bias_s[i] = rel_emb[i * 8 + h] * 1.44269504f;
  __syncthreads();
  const float bias_lo = bias_s[0], bias_hi = bias_s[256];

  const int lane = tid & 63, w = tid >> 6;
  const int hi = lane >> 5, q31 = lane & 31;
  const int q0w = qb * 128 + w * 32;
  const int tq = q0w + q31;
  const float SCL = 0.125f * 1.44269504f;  // 1/sqrt(64) * log2(e)

  const unsigned short* qptr = Qp + (size_t)(b * 2048 + tq) * 512 + h * 64 + hi * 8;
  const bf16x8 qf0 = ld_bf8(qptr);
  const bf16x8 qf1 = ld_bf8(qptr + 16);
  const bf16x8 qf2 = ld_bf8(qptr + 32);
  const bf16x8 qf3 = ld_bf8(qptr + 48);

  const unsigned short* kbase = Kp + (size_t)(b * 2048) * 512 + h * 64 + hi * 8;
  const unsigned short* vb_lo = Vt + (((size_t)((b * 8 + h) * 64 + q31)) << 11) + hi * 8;
  const unsigned short* vb_hi = vb_lo + ((size_t)32 << 11);

  const f32x16 z16 = {0.f, 0.f, 0.f, 0.f, 0.f, 0.f, 0.f, 0.f,
                      0.f, 0.f, 0.f, 0.f, 0.f, 0.f, 0.f, 0.f};
  f32x16 o_lo = z16, o_hi = z16;
  float m_run = -1e30f, l_run = 0.f;
  f32x16 sa, sb;

  // bias + scale + max + defer-rescale + exp2 + sum, in place on sa/sb
  auto softmax_part = [&](int s0) {
    const int relmin = q0w - s0 - 63;
    const int relmax = q0w + 31 - s0;
    if (relmin >= 128 || relmax <= -128) {
      const float bc = (relmin >= 128) ? bias_hi : bias_lo;
#pragma unroll
      for (int r = 0; r < 16; r++) {
        sa[r] = fmaf(sa[r], SCL, bc);
        sb[r] = fmaf(sb[r], SCL, bc);
      }
    } else {
#pragma unroll
      for (int r = 0; r < 16; r++) {
        const int rowA = (r & 3) + 8 * (r >> 2) + 4 * hi;
        const int rA = tq - s0 - rowA;
        const int rB = rA - 32;
        const int iA = (rA < -128 ? -128 : (rA > 128 ? 128 : rA)) + 128;
        const int iB = (rB < -128 ? -128 : (rB > 128 ? 128 : rB)) + 128;
        sa[r] = fmaf(sa[r], SCL, bias_s[iA]);
        sb[r] = fmaf(sb[r], SCL, bias_s[iB]);
      }
    }
    // max tree in max3-fusable triples
    const float t0 = fmaxf(fmaxf(sa[0], sa[1]), sa[2]);
    const float t1 = fmaxf(fmaxf(sa[3], sa[4]), sa[5]);
    const float t2 = fmaxf(fmaxf(sa[6], sa[7]), sa[8]);
    const float t3 = fmaxf(fmaxf(sa[9], sa[10]), sa[11]);
    const float t4 = fmaxf(fmaxf(sa[12], sa[13]), sa[14]);
    const float t5 = fmaxf(fmaxf(sa[15], sb[0]), sb[1]);
    const float t6 = fmaxf(fmaxf(sb[2], sb[3]), sb[4]);
    const float t7 = fmaxf(fmaxf(sb[5], sb[6]), sb[7]);
    const float t8 = fmaxf(fmaxf(sb[8], sb[9]), sb[10]);
    const float t9 = fmaxf(fmaxf(sb[11], sb[12]), sb[13]);
    const float ta = fmaxf(sb[14], sb[15]);
    const float u0 = fmaxf(fmaxf(t0, t1), t2);
    const float u1 = fmaxf(fmaxf(t3, t4), t5);
    const float u2 = fmaxf(fmaxf(t6, t7), t8);
    float mx = fmaxf(fmaxf(fmaxf(u0, u1), u2), fmaxf(t9, ta));
    mx = fmaxf(mx, __shfl_xor(mx, 32, 64));

    if (!__all(mx <= m_run + 8.f)) {
      const float m_new = fmaxf(m_run, mx);
      const float rsq = exp2f(m_run - m_new);
      l_run *= rsq;
      m_run = m_new;
#pragma unroll
      for (int r2 = 0; r2 < 16; r2++) {
        const int ro = (r2 & 3) + 8 * (r2 >> 2) + 4 * hi;
        const float rr = __shfl(rsq, ro, 64);
        o_lo[r2] *= rr;
        o_hi[r2] *= rr;
      }
    }

#pragma unroll
    for (int r = 0; r < 16; r++) {
      sa[r] = exp2f(sa[r] - m_run);
      sb[r] = exp2f(sb[r] - m_run);
    }
    float s8[8];
#pragma unroll
    for (int i = 0; i < 8; i++)
      s8[i] = (sa[i] + sa[i + 8]) + (sb[i] + sb[i + 8]);
    float ps = ((s8[0] + s8[1]) + (s8[2] + s8[3])) + ((s8[4] + s8[5]) + (s8[6] + s8[7]));
    ps += __shfl_xor(ps, 32, 64);
    l_run += ps;
  };

  // P(sa/sb) -> bf16 A-fragments, then PV accumulate
  auto cvt_pv = [&](const bf16x8 vl[4], const bf16x8 vh[4]) {
    bf16x8 pa[4];
#pragma unroll
    for (int ks = 0; ks < 4; ks++) {
      const int c8 = (ks & 1) * 8;
      const f32x16& src = (ks < 2) ? sa : sb;
      unsigned int a0 = cvt_pk_bf16(src[c8 + 0], src[c8 + 1]);
      unsigned int b0 = cvt_pk_bf16(src[c8 + 4], src[c8 + 5]);
      unsigned int a1 = cvt_pk_bf16(src[c8 + 2], src[c8 + 3]);
      unsigned int b1 = cvt_pk_bf16(src[c8 + 6], src[c8 + 7]);
      plane32_swap(a0, b0);
      plane32_swap(a1, b1);
      pa[ks] = __builtin_bit_cast(bf16x8, u32x4{a0, a1, b0, b1});
    }
#pragma unroll
    for (int ks = 0; ks < 4; ks++) {
      o_lo = mfma32(pa[ks], vl[ks], o_lo);
      o_hi = mfma32(pa[ks], vh[ks], o_hi);
    }
  };

  // ---- prologue: K(0) + QK(0) ----
  {
    const unsigned short* krA = kbase + (size_t)q31 * 512;
    bf16x8 k0[8];
#pragma unroll
    for (int c = 0; c < 4; c++) {
      k0[c] = ld_bf8(krA + c * 16);
      k0[4 + c] = ld_bf8(krA + 32 * 512 + c * 16);
    }
    sa = mfma32(k0[0], qf0, z16); sb = mfma32(k0[4], qf0, z16);
    sa = mfma32(k0[1], qf1, sa);  sb = mfma32(k0[5], qf1, sb);
    sa = mfma32(k0[2], qf2, sa);  sb = mfma32(k0[6], qf2, sb);
    sa = mfma32(k0[3], qf3, sa);  sb = mfma32(k0[7], qf3, sb);
  }

  // ---- main loop: tiles 0..30 with tile t+1 prefetch+QK overlap ----
  for (int t = 0; t < 31; ++t) {
    const int s0 = t * 64;
    const int s1 = s0 + 64;
    // issue K(t+1) loads
    bf16x8 kn[8];
    const unsigned short* krA = kbase + (size_t)(s1 + q31) * 512;
#pragma unroll
    for (int c = 0; c < 4; c++) {
      kn[c] = ld_bf8(krA + c * 16);
      kn[4 + c] = ld_bf8(krA + 32 * 512 + c * 16);
    }
    // issue V(t) loads
    bf16x8 vl[4], vh[4];
#pragma unroll
    for (int ks = 0; ks < 4; ks++) {
      vl[ks] = ld_bf8(vb_lo + s0 + ks * 16);
      vh[ks] = ld_bf8(vb_hi + s0 + ks * 16);
    }

    softmax_part(s0);  // VALU; overlaps K(t+1)/V(t) load latency

    // QK^T(t+1): MFMA pipe busy while cvt_pv's VALU runs after
    f32x16 sa_n, sb_n;
    sa_n = mfma32(kn[0], qf0, z16); sb_n = mfma32(kn[4], qf0, z16);
    sa_n = mfma32(kn[1], qf1, sa_n); sb_n = mfma32(kn[5], qf1, sb_n);
    sa_n = mfma32(kn[2], qf2, sa_n); sb_n = mfma32(kn[6], qf2, sb_n);
    sa_n = mfma32(kn[3], qf3, sa_n); sb_n = mfma32(kn[7], qf3, sb_n);

    cvt_pv(vl, vh);

    sa = sa_n; sb = sb_n;
  }

  // ---- tail tile (t = 31) ----
  {
    const int s0 = 1984;
    bf16x8 vl[4], vh[4];
#pragma unroll
    for (int ks = 0; ks < 4; ks++) {
      vl[ks] = ld_bf8(vb_lo + s0 + ks * 16);
      vh[ks] = ld_bf8(vb_hi + s0 + ks * 16);
    }
    softmax_part(s0);
    cvt_pv(vl, vh);
  }

  // ---- normalize + write ----
  const float inv = 1.f / l_run;
#pragma unroll
  for (int r2 = 0; r2 < 16; r2++) {
    const int ro = (r2 & 3) + 8 * (r2 >> 2) + 4 * hi;
    const float rr = __shfl(inv, ro, 64);
    unsigned short* op = Out + (size_t)(b * 2048 + q0w + ro) * 512 + h * 64;
    op[q31] = f2bf(o_lo[r2] * rr);
    op[32 + q31] = f2bf(o_hi[r2] * rr);
  }
}

// ---------------- host ----------------
extern "C" void kernel_launch(void* const* d_in, const int* in_sizes, int n_in,
                              void* d_out, int out_size, void* d_ws, size_t ws_size,
                              hipStream_t stream) {
  const float* query = (const float*)d_in[0];
  const float* key   = (const float*)d_in[1];
  const float* value = (const float*)d_in[2];
  const float* Wq = (const float*)d_in[3];
  const float* bq = (const float*)d_in[4];
  const float* Wk = (const float*)d_in[5];
  const float* bk = (const float*)d_in[6];
  const float* Wv = (const float*)d_in[7];
  const float* bv = (const float*)d_in[8];
  const float* Wo = (const float*)d_in[9];
  const float* bo = (const float*)d_in[10];
  const float* rel = (const float*)d_in[11];

  char* ws = (char*)d_ws;
  const size_t SZX = (size_t)4 * 2048 * 512;
  const size_t SZW = (size_t)512 * 512;
  unsigned short* xq = (unsigned short*)ws;
  unsigned short* xk = xq + SZX;
  unsigned short* xv = xk + SZX;
  unsigned short* wq = xv + SZX;
  unsigned short* wk = wq + SZW;
  unsigned short* wv = wk + SZW;
  unsigned short* wo = wv + SZW;
  unsigned short* Qp = wo + SZW;
  unsigned short* Kp = Qp + SZX;
  unsigned short* Vt = Kp + SZX;
  unsigned short* At = Vt + SZX;

  auto cvt = [&](const float* s, unsigned short* dst, int n) {
    cvt_kernel<<<dim3((n + 1023) / 1024), dim3(256), 0, stream>>>(s, dst, n);
  };
  cvt(query, xq, (int)SZX);
  cvt(key, xk, (int)SZX);
  cvt(value, xv, (int)SZX);
  cvt(Wq, wq, (int)SZW);
  cvt(Wk, wk, (int)SZW);
  cvt(Wv, wv, (int)SZW);
  cvt(Wo, wo, (int)SZW);

  dim3 gg(4, 64), blk(256);
  gemm_bt<0><<<gg, blk, 0, stream>>>(xq, wq, bq, (void*)Qp);
  gemm_bt<0><<<gg, blk, 0, stream>>>(xk, wk, bk, (void*)Kp);
  gemm_bt<1><<<gg, blk, 0, stream>>>(xv, wv, bv, (void*)Vt);

  attn_kernel<<<dim3(512), blk, 0, stream>>>(Qp, Kp, Vt, rel, At);

  gemm_bt<2><<<gg, blk, 0, stream>>>(At, wo, bo, d_out);
}